// Round 15
// baseline (186.579 us; speedup 1.0000x reference)
//
#include <hip/hip_runtime.h>
#include <stdint.h>

#define B_Q     4096
#define N_SLOTS 32768
#define KD      128
#define BM      64                   // rows per block (4-wave blocks)
#define BN      128
#define NSPLIT  32
#define NCHUNK  (N_SLOTS / NSPLIT)   // 1024 cols per block
#define NT_BLK  (NCHUNK / BN)        // 8 tiles per block
#define CAND_CAP (1 << 20)           // 1M record cap (u64)
#define LCAP    2048                 // per-block LDS record cap (16 KB)
#define KPANELS (N_SLOTS / 16)       // 2048
#define QPANELS (B_Q / 16)           // 256

typedef _Float16 f16x8 __attribute__((ext_vector_type(8)));
typedef float    f32x4 __attribute__((ext_vector_type(4)));

// ordered-float: monotone f32 <-> u32
__device__ __forceinline__ unsigned int ord_f32(float f) {
    unsigned int u = __float_as_uint(f);
    return (u & 0x80000000u) ? ~u : (u | 0x80000000u);
}
__device__ __forceinline__ float ord_inv(unsigned int u) {
    unsigned int b = (u & 0x80000000u) ? (u & 0x7FFFFFFFu) : ~u;
    return __uint_as_float(b);
}

__device__ __forceinline__ unsigned long long shfl_xor_u64(unsigned long long v, int mask, int width) {
    unsigned int lo = (unsigned int)v, hi = (unsigned int)(v >> 32);
    lo = __shfl_xor(lo, mask, width);
    hi = __shfl_xor(hi, mask, width);
    return ((unsigned long long)hi << 32) | lo;
}

// max over the 16-lane DPP row via 4x ROW_ROR rotate-reduce (no LDS traffic)
__device__ __forceinline__ float rowmax16(float x) {
    x = fmaxf(x, __int_as_float(__builtin_amdgcn_mov_dpp(__float_as_int(x), 0x128, 0xf, 0xf, true)));
    x = fmaxf(x, __int_as_float(__builtin_amdgcn_mov_dpp(__float_as_int(x), 0x124, 0xf, 0xf, true)));
    x = fmaxf(x, __int_as_float(__builtin_amdgcn_mov_dpp(__float_as_int(x), 0x122, 0xf, 0xf, true)));
    x = fmaxf(x, __int_as_float(__builtin_amdgcn_mov_dpp(__float_as_int(x), 0x121, 0xf, 0xf, true)));
    return x;
}

// ---------------- prep: normalize K, f16-convert, pack into MFMA-fragment order ----
// [R10/R14-verified verbatim]
__global__ void prep_pack(const float* __restrict__ Q, const float* __restrict__ Kb,
                          uint4* __restrict__ qp, uint4* __restrict__ kp,
                          float* __restrict__ mg, float* __restrict__ ik,
                          unsigned int* __restrict__ glb,
                          unsigned long long* __restrict__ best2, int* __restrict__ cnt) {
    const int gid = blockIdx.x * blockDim.x + threadIdx.x;
    if (gid < B_Q) { best2[gid] = 0ull; glb[gid] = 0u; }
    if (gid == 0) { cnt[0] = 0; cnt[1] = 0; cnt[2] = 0; cnt[3] = 0; }

    const int p = blockIdx.x;            // panel id: [0,KPANELS) K, then Q
    const int t = threadIdx.x;           // r = t>>4 rows, c = t&15 k-16ths
    const int r = t >> 4, c = t & 15;
    const bool isK = p < KPANELS;
    const int row = isK ? p * 16 + r : (p - KPANELS) * 16 + r;
    const float* src = isK ? Kb : Q;
    const float4* rp = reinterpret_cast<const float4*>(src + (size_t)row * KD);
    const float4 va = rp[c * 2], vb = rp[c * 2 + 1];   // els k = c*8 .. c*8+7
    float ss = va.x * va.x + va.y * va.y + va.z * va.z + va.w * va.w
             + vb.x * vb.x + vb.y * vb.y + vb.z * vb.z + vb.w * vb.w;
    #pragma unroll
    for (int m = 8; m; m >>= 1) ss += __shfl_xor(ss, m, 16);   // 16 threads per row
    const float nrm = fmaxf(sqrtf(ss), 1e-12f);
    const float scale = isK ? 1.0f / nrm : 1.0f;
    if (c == 0) {
        if (isK) ik[row] = scale;
        else     mg[row] = nrm * 2.2e-3f;   // rigorous: >= 2*eps_f16dot (2^-10*||q||)
    }
    unsigned short h[8];
    const float e[8] = {va.x, va.y, va.z, va.w, vb.x, vb.y, vb.z, vb.w};
    #pragma unroll
    for (int i = 0; i < 8; ++i) {
        _Float16 hv = (_Float16)(e[i] * scale);
        __builtin_memcpy(&h[i], &hv, 2);
    }
    uint4 out;
    out.x = (unsigned)h[0] | ((unsigned)h[1] << 16);
    out.y = (unsigned)h[2] | ((unsigned)h[3] << 16);
    out.z = (unsigned)h[4] | ((unsigned)h[5] << 16);
    out.w = (unsigned)h[6] | ((unsigned)h[7] << 16);
    uint4* dst = isK ? kp : qp;
    const int pl = isK ? p : p - KPANELS;
    dst[(size_t)(pl * 4 + (c >> 2)) * 64 + (c & 3) * 16 + r] = out;
}

// ---------------- pass 1: f16 MFMA GEMM (packed global frags) + margin records ----
// 2048 blocks x 256 threads (4 waves, 1 wave/SIMD each -> 5 blocks/CU by the
// 96-unified-reg budget: +25% TLP over R14's 512-thr blocks). Wave w: rows
// q0+(w>>1)*32, cols n0+(w&1)*64; block tile 64x128. XCD decode: xcd=bid&7 owns
// n-chunks 4*xcd..4*xcd+3. Per-tile glb COUPLING: atomicMax publish returns the
// old global max, folded into L for the next tile (cross-block shared running
// max -> short per-block chains don't inflate records at NT_BLK=8). Correctness:
// L only ever holds genuine f16 scores <= M16, so the winner clears L - m.
__global__ __launch_bounds__(256, 5) void pass1_kernel(
    const uint4* __restrict__ qp, const uint4* __restrict__ kp,
    const float* __restrict__ mg_g, unsigned int* __restrict__ glb,
    int* __restrict__ cnt, unsigned long long* __restrict__ recs)
{
    __shared__ unsigned long long lbuf[LCAP];
    __shared__ int lcnt;
    __shared__ int sbase;

    const int bid  = blockIdx.x;
    const int q0   = (bid >> 5) * BM;
    const int n0   = ((bid & 7) * 4 + ((bid >> 3) & 3)) * NCHUNK;
    const int tid  = threadIdx.x;
    const int lane = tid & 63;
    const int w    = tid >> 6;      // 0..3
    const int wr   = w >> 1;        // 0..1: row group (32 rows)
    const int wc   = w & 1;         // 0..1: col group (64 cols)
    const int l15  = lane & 15;
    const int lg   = lane >> 4;

    if (tid == 0) lcnt = 0;
    __syncthreads();

    // per-lane owned rows: row(e) = q0 + wr*32 + (e>>2)*16 + lg*4 + (e&3), e<8
    float L[8], mgv[8];
    #pragma unroll
    for (int e = 0; e < 8; ++e) {
        const int row = q0 + wr * 32 + (e >> 2) * 16 + lg * 4 + (e & 3);
        mgv[e] = mg_g[row];
        const unsigned int g = glb[row];
        L[e] = g ? ord_inv(g) : -3e38f;
    }

    // A fragments (Q) cached in registers: panels (q0>>4) + wr*2 + i
    f16x8 aq[2][4];
    #pragma unroll
    for (int i = 0; i < 2; ++i)
        #pragma unroll
        for (int kc = 0; kc < 4; ++kc)
            aq[i][kc] = *(const f16x8*)&qp[(size_t)(((q0 >> 4) + wr * 2 + i) * 4 + kc) * 64 + lane];

    const int pbase = (n0 >> 4) + wc * 4;   // first k-panel for this wave's half

    #pragma unroll 1
    for (int t = 0; t < NT_BLK; ++t) {
        const int nb = n0 + t * BN;

        f32x4 acc[2][4];
        #pragma unroll
        for (int i = 0; i < 2; ++i)
            #pragma unroll
            for (int j = 0; j < 4; ++j) {
                acc[i][j][0] = 0.f; acc[i][j][1] = 0.f;
                acc[i][j][2] = 0.f; acc[i][j][3] = 0.f;
            }

        #pragma unroll
        for (int kc = 0; kc < 4; ++kc) {
            f16x8 bh[4];
            #pragma unroll
            for (int j = 0; j < 4; ++j)
                bh[j] = *(const f16x8*)&kp[(size_t)((pbase + t * 8 + j) * 4 + kc) * 64 + lane];
            #pragma unroll
            for (int i = 0; i < 2; ++i)
                #pragma unroll
                for (int j = 0; j < 4; ++j)
                    acc[i][j] = __builtin_amdgcn_mfma_f32_16x16x32_f16(aq[i][kc], bh[j], acc[i][j], 0, 0, 0);
        }

        // fold row-max, DPP-share, gated append of near-max records
        #pragma unroll
        for (int e = 0; e < 8; ++e) {
            const int i = e >> 2, rr = e & 3;
            const float me = fmaxf(fmaxf(fmaxf(acc[i][0][rr], acc[i][1][rr]),
                                         acc[i][2][rr]), acc[i][3][rr]);
            L[e] = rowmax16(fmaxf(L[e], me));
            const float th = L[e] - mgv[e];
            if (me >= th) {
                const int row = q0 + wr * 32 + i * 16 + lg * 4 + rr;
                #pragma unroll
                for (int j = 0; j < 4; ++j) {
                    const float v = acc[i][j][rr];
                    if (v >= th) {
                        const int n = nb + wc * 64 + j * 16 + l15;
                        const int pos = atomicAdd(&lcnt, 1);
                        if (pos < LCAP)
                            lbuf[pos] = ((unsigned long long)ord_f32(v) << 32)
                                      | (unsigned int)((row << 15) | n);
                    }
                }
            }
        }

        // glb coupling: publish this tile's L, pull other blocks' maxima for
        // the NEXT tile's gate (atomicMax returns old value; next tile's
        // rowmax16 spreads the tightened bound to all 16 lanes of the row)
        if (l15 == 0) {
            #pragma unroll
            for (int e = 0; e < 8; ++e) {
                const int row = q0 + wr * 32 + (e >> 2) * 16 + lg * 4 + (e & 3);
                const unsigned int old = atomicMax(&glb[row], ord_f32(L[e]));
                if (old) L[e] = fmaxf(L[e], ord_inv(old));
            }
        }
    }

    // flush records: ONE global atomic per block
    __syncthreads();
    const int total = lcnt;
    const int nout  = total < LCAP ? total : LCAP;
    if (tid == 0) {
        const int base = atomicAdd(&cnt[0], nout);
        sbase = base;
        if (total > LCAP || base + nout > CAND_CAP) atomicOr(&cnt[1], 1);
    }
    __syncthreads();
    for (int c = tid; c < nout; c += 256) {
        const int g = sbase + c;
        if (g < CAND_CAP) recs[g] = lbuf[c];
    }
}

// ---------------- fused filter+rescore [R12/R14-verified verbatim] ----
__global__ void filter_rescore_kernel(const unsigned long long* __restrict__ recs,
                                      const unsigned int* __restrict__ glb,
                                      const float* __restrict__ mg_g,
                                      int* __restrict__ cnt,
                                      const float* __restrict__ Q, const float* __restrict__ Kb,
                                      const float* __restrict__ ik,
                                      unsigned long long* __restrict__ best2)
{
    __shared__ unsigned int sb[2048];
    __shared__ int sc;
    const int tid = threadIdx.x;
    if (tid == 0) sc = 0;
    __syncthreads();

    const int cn = cnt[0];
    const int count = cn < CAND_CAP ? cn : CAND_CAP;
    const int nthr = gridDim.x * blockDim.x;
    for (int c = blockIdx.x * blockDim.x + tid; c < count; c += nthr) {
        const unsigned long long rec = recs[c];
        const unsigned int lo = (unsigned int)rec;
        const int q = (int)(lo >> 15);
        const float s = ord_inv((unsigned int)(rec >> 32));
        const unsigned int g = glb[q];
        const float M = g ? ord_inv(g) : 3e38f;   // unwritten row -> no survivors; safety rescues
        if (s >= M - mg_g[q]) {
            const int pos = atomicAdd(&sc, 1);
            if (pos < 2048) sb[pos] = lo;
        }
    }
    __syncthreads();
    const int total = sc;
    const int nout  = total < 2048 ? total : 2048;
    if (total > 2048 && tid == 0) atomicOr(&cnt[1], 2);   // overflow -> bad path

    const int lane = tid & 63;
    const int l15  = lane & 15;
    const int grp  = (tid >> 6) * 4 + (lane >> 4);
    const int ngrp = (blockDim.x >> 6) * 4;
    for (int c = grp; c < nout; c += ngrp) {
        const unsigned int lo = sb[c];
        const int q = (int)(lo >> 15), n = (int)(lo & 32767u);
        const float4* qpr = (const float4*)(Q  + (size_t)q * KD);
        const float4* kpr = (const float4*)(Kb + (size_t)n * KD);
        const float4 qa = qpr[l15 * 2], qb = qpr[l15 * 2 + 1];
        const float4 ka = kpr[l15 * 2], kb = kpr[l15 * 2 + 1];
        float dot = qa.x * ka.x + qa.y * ka.y + qa.z * ka.z + qa.w * ka.w
                  + qb.x * kb.x + qb.y * kb.y + qb.z * kb.z + qb.w * kb.w;
        #pragma unroll
        for (int m = 8; m; m >>= 1) dot += __shfl_xor(dot, m, 16);
        if (l15 == 0) {
            const float v = dot * ik[n];
            const unsigned long long pk =
                ((unsigned long long)ord_f32(v) << 32) | (unsigned int)(~n);
            atomicMax(&best2[q], pk);
        }
    }
}

// ---------------- fused safety+decode [R12/R14-verified verbatim] ----
__global__ void safety_decode_kernel(const float* __restrict__ Q, const float* __restrict__ Kb,
                                     const float* __restrict__ ik, const int* __restrict__ cnt,
                                     const unsigned long long* __restrict__ best2,
                                     int* __restrict__ out) {
    const int lane = threadIdx.x & 63;
    const int wid  = (blockIdx.x * blockDim.x + threadIdx.x) >> 6;
    const int nw   = (gridDim.x * blockDim.x) >> 6;
    const bool bad = (cnt[1] != 0) || (cnt[0] > CAND_CAP);
    for (int q = wid; q < B_Q; q += nw) {
        const unsigned long long b = best2[q];
        if (!bad && b != 0ull) {
            if (lane == 0) out[q] = (int)(~(unsigned int)(b & 0xFFFFFFFFull));
            continue;
        }
        // exhaustive exact scan (never taken for bench inputs)
        const float* qr = Q + (size_t)q * KD;
        unsigned long long pb = 0ull;
        for (int n = lane; n < N_SLOTS; n += 64) {
            const float* kr = Kb + (size_t)n * KD;
            float dot = 0.f;
            for (int d = 0; d < KD; ++d) dot = fmaf(qr[d], kr[d], dot);
            const float v = dot * ik[n];
            const unsigned long long p =
                ((unsigned long long)ord_f32(v) << 32) | (unsigned int)(~n);
            if (p > pb) pb = p;
        }
        #pragma unroll
        for (int m = 32; m; m >>= 1) {
            const unsigned long long o = shfl_xor_u64(pb, m, 64);
            if (o > pb) pb = o;
        }
        if (lane == 0) out[q] = (int)(~(unsigned int)(pb & 0xFFFFFFFFull));
    }
}

// ---------------- ws-too-small fallback: slow but correct ----------------
__global__ void fallback_kernel(const float* __restrict__ Q, const float* __restrict__ Kb,
                                int* __restrict__ out) {
    __shared__ float q[KD];
    __shared__ unsigned long long red[256];
    const int b = blockIdx.x;
    for (int i = threadIdx.x; i < KD; i += 256) q[i] = Q[(size_t)b * KD + i];
    __syncthreads();
    unsigned long long pbest = 0ull;
    for (int n = threadIdx.x; n < N_SLOTS; n += 256) {
        const float* kr = Kb + (size_t)n * KD;
        float dot = 0.f, ss = 0.f;
        for (int d = 0; d < KD; ++d) { float kv = kr[d]; dot = fmaf(q[d], kv, dot); ss = fmaf(kv, kv, ss); }
        float v = dot / fmaxf(sqrtf(ss), 1e-12f);
        unsigned long long p = ((unsigned long long)ord_f32(v) << 32) | (unsigned int)(~n);
        if (p > pbest) pbest = p;
    }
    red[threadIdx.x] = pbest; __syncthreads();
    for (int s = 128; s; s >>= 1) {
        if (threadIdx.x < (unsigned)s && red[threadIdx.x + s] > red[threadIdx.x])
            red[threadIdx.x] = red[threadIdx.x + s];
        __syncthreads();
    }
    if (threadIdx.x == 0) out[b] = (int)(~(unsigned int)(red[0] & 0xFFFFFFFFull));
}

extern "C" void kernel_launch(void* const* d_in, const int* in_sizes, int n_in,
                              void* d_out, int out_size, void* d_ws, size_t ws_size,
                              hipStream_t stream) {
    const float* Q  = (const float*)d_in[0];   // 4096 x 128
    const float* Kb = (const float*)d_in[1];   // 32768 x 128
    int* out = (int*)d_out;

    const size_t QP_B = (size_t)B_Q * KD * 2;        // 1 MB packed Q (f16)
    const size_t KP_B = (size_t)N_SLOTS * KD * 2;    // 8 MB packed K (f16)
    const size_t MG_B = (size_t)B_Q * 4;             // 16 KB
    const size_t IK_B = (size_t)N_SLOTS * 4;         // 128 KB
    const size_t GL_B = (size_t)B_Q * 4;             // 16 KB
    const size_t B2_B = (size_t)B_Q * 8;             // 32 KB
    const size_t CNT_B = 256;
    const size_t REC_B = (size_t)CAND_CAP * 8;       // 8 MB
    const size_t NEED = QP_B + KP_B + MG_B + IK_B + GL_B + B2_B + CNT_B + REC_B;

    if (ws_size < NEED) {
        fallback_kernel<<<B_Q, 256, 0, stream>>>(Q, Kb, out);
        return;
    }

    char* p = (char*)d_ws;
    uint4*          qp  = (uint4*)p;                     p += QP_B;
    uint4*          kp  = (uint4*)p;                     p += KP_B;
    float*          mg  = (float*)p;                     p += MG_B;
    float*          ik  = (float*)p;                     p += IK_B;
    unsigned int*   glb = (unsigned int*)p;              p += GL_B;
    unsigned long long* best2 = (unsigned long long*)p;  p += B2_B;
    int*            cnt = (int*)p;                       p += CNT_B;
    unsigned long long* recs = (unsigned long long*)p;

    prep_pack<<<KPANELS + QPANELS, 256, 0, stream>>>(Q, Kb, qp, kp, mg, ik, glb, best2, cnt);
    pass1_kernel<<<2048, 256, 0, stream>>>(qp, kp, mg, glb, cnt, recs);
    filter_rescore_kernel<<<256, 256, 0, stream>>>(recs, glb, mg, cnt, Q, Kb, ik, best2);
    safety_decode_kernel<<<64, 256, 0, stream>>>(Q, Kb, ik, cnt, best2, out);
}

// Round 16
// 86.552 us; speedup vs baseline: 2.1557x; 2.1557x over previous
//
#include <hip/hip_runtime.h>
#include <stdint.h>

#define B_Q     4096
#define N_SLOTS 32768
#define KD      128
#define BM      128
#define BN      128
#define NSPLIT  16
#define NCHUNK  (N_SLOTS / NSPLIT)   // 2048 cols per block
#define NT_BLK  (NCHUNK / BN)        // 16 tiles per block
#define CAND_CAP (1 << 20)           // 1M record cap (u64)
#define LCAP    6144                 // per-block LDS record cap (48 KB)
#define KPANELS (N_SLOTS / 16)       // 2048
#define QPANELS (B_Q / 16)           // 256

typedef _Float16 f16x8 __attribute__((ext_vector_type(8)));
typedef float    f32x4 __attribute__((ext_vector_type(4)));

// ordered-float: monotone f32 <-> u32
__device__ __forceinline__ unsigned int ord_f32(float f) {
    unsigned int u = __float_as_uint(f);
    return (u & 0x80000000u) ? ~u : (u | 0x80000000u);
}
__device__ __forceinline__ float ord_inv(unsigned int u) {
    unsigned int b = (u & 0x80000000u) ? (u & 0x7FFFFFFFu) : ~u;
    return __uint_as_float(b);
}

__device__ __forceinline__ unsigned long long shfl_xor_u64(unsigned long long v, int mask, int width) {
    unsigned int lo = (unsigned int)v, hi = (unsigned int)(v >> 32);
    lo = __shfl_xor(lo, mask, width);
    hi = __shfl_xor(hi, mask, width);
    return ((unsigned long long)hi << 32) | lo;
}

// max over the 16-lane DPP row via 4x ROW_ROR rotate-reduce (no LDS traffic)
__device__ __forceinline__ float rowmax16(float x) {
    x = fmaxf(x, __int_as_float(__builtin_amdgcn_mov_dpp(__float_as_int(x), 0x128, 0xf, 0xf, true)));
    x = fmaxf(x, __int_as_float(__builtin_amdgcn_mov_dpp(__float_as_int(x), 0x124, 0xf, 0xf, true)));
    x = fmaxf(x, __int_as_float(__builtin_amdgcn_mov_dpp(__float_as_int(x), 0x122, 0xf, 0xf, true)));
    x = fmaxf(x, __int_as_float(__builtin_amdgcn_mov_dpp(__float_as_int(x), 0x121, 0xf, 0xf, true)));
    return x;
}

// ---------------- prep: normalize K, f16-convert, pack into MFMA-fragment order ----
// Packed unit (16B) index: (panel*4 + kc)*64 + lg*16 + r, holding row panel*16+r,
// k = kc*32 + lg*8 .. +8.  One block per 16-row panel. Also zeroes glb/best2/cnt.
// [R10/R14-verified verbatim]
__global__ void prep_pack(const float* __restrict__ Q, const float* __restrict__ Kb,
                          uint4* __restrict__ qp, uint4* __restrict__ kp,
                          float* __restrict__ mg, float* __restrict__ ik,
                          unsigned int* __restrict__ glb,
                          unsigned long long* __restrict__ best2, int* __restrict__ cnt) {
    const int gid = blockIdx.x * blockDim.x + threadIdx.x;
    if (gid < B_Q) { best2[gid] = 0ull; glb[gid] = 0u; }
    if (gid == 0) { cnt[0] = 0; cnt[1] = 0; cnt[2] = 0; cnt[3] = 0; }

    const int p = blockIdx.x;            // panel id: [0,KPANELS) K, then Q
    const int t = threadIdx.x;           // r = t>>4 rows, c = t&15 k-16ths
    const int r = t >> 4, c = t & 15;
    const bool isK = p < KPANELS;
    const int row = isK ? p * 16 + r : (p - KPANELS) * 16 + r;
    const float* src = isK ? Kb : Q;
    const float4* rp = reinterpret_cast<const float4*>(src + (size_t)row * KD);
    const float4 va = rp[c * 2], vb = rp[c * 2 + 1];   // els k = c*8 .. c*8+7
    float ss = va.x * va.x + va.y * va.y + va.z * va.z + va.w * va.w
             + vb.x * vb.x + vb.y * vb.y + vb.z * vb.z + vb.w * vb.w;
    #pragma unroll
    for (int m = 8; m; m >>= 1) ss += __shfl_xor(ss, m, 16);   // 16 threads per row
    const float nrm = fmaxf(sqrtf(ss), 1e-12f);
    const float scale = isK ? 1.0f / nrm : 1.0f;
    if (c == 0) {
        if (isK) ik[row] = scale;
        else     mg[row] = nrm * 2.2e-3f;   // rigorous: >= 2*eps_f16dot (2^-10*||q||)
    }
    unsigned short h[8];
    const float e[8] = {va.x, va.y, va.z, va.w, vb.x, vb.y, vb.z, vb.w};
    #pragma unroll
    for (int i = 0; i < 8; ++i) {
        _Float16 hv = (_Float16)(e[i] * scale);
        __builtin_memcpy(&h[i], &hv, 2);
    }
    uint4 out;
    out.x = (unsigned)h[0] | ((unsigned)h[1] << 16);
    out.y = (unsigned)h[2] | ((unsigned)h[3] << 16);
    out.z = (unsigned)h[4] | ((unsigned)h[5] << 16);
    out.w = (unsigned)h[6] | ((unsigned)h[7] << 16);
    uint4* dst = isK ? kp : qp;
    const int pl = isK ? p : p - KPANELS;
    dst[(size_t)(pl * 4 + (c >> 2)) * 64 + (c & 3) * 16 + r] = out;
}

// ---------------- pass 1: f16 MFMA GEMM (packed global frags) + margin records ----
// [R10/R14-verified verbatim: 68 us, VGPR 64, no spill, FETCH 8.4 MB]
// 512 blocks x 512 threads (8 waves). Wave w: rows q0+(w>>1)*32, cols n0+(w&1)*64.
// XCD decode: xcd=bid&7 owns n-chunks {2*xcd, 2*xcd+1}.
__global__ __launch_bounds__(512, 4) void pass1_kernel(
    const uint4* __restrict__ qp, const uint4* __restrict__ kp,
    const float* __restrict__ mg_g, unsigned int* __restrict__ glb,
    int* __restrict__ cnt, unsigned long long* __restrict__ recs)
{
    __shared__ unsigned long long lbuf[LCAP];
    __shared__ int lcnt;
    __shared__ int sbase;

    const int bid  = blockIdx.x;
    const int q0   = (bid >> 4) * BM;
    const int n0   = ((bid & 7) * 2 + ((bid >> 3) & 1)) * NCHUNK;
    const int tid  = threadIdx.x;
    const int lane = tid & 63;
    const int w    = tid >> 6;      // 0..7
    const int wr   = w >> 1;        // 0..3: row group (32 rows)
    const int wc   = w & 1;         // 0..1: col group (64 cols)
    const int l15  = lane & 15;
    const int lg   = lane >> 4;

    if (tid == 0) lcnt = 0;
    __syncthreads();

    // per-lane owned rows: row(e) = q0 + wr*32 + (e>>2)*16 + lg*4 + (e&3), e<8
    float L[8], mgv[8];
    #pragma unroll
    for (int e = 0; e < 8; ++e) {
        const int row = q0 + wr * 32 + (e >> 2) * 16 + lg * 4 + (e & 3);
        mgv[e] = mg_g[row];
        const unsigned int g = glb[row];
        L[e] = g ? ord_inv(g) : -3e38f;
    }

    // A fragments (Q) cached in registers: panels (q0>>4) + wr*2 + i
    f16x8 aq[2][4];
    #pragma unroll
    for (int i = 0; i < 2; ++i)
        #pragma unroll
        for (int kc = 0; kc < 4; ++kc)
            aq[i][kc] = *(const f16x8*)&qp[(size_t)(((q0 >> 4) + wr * 2 + i) * 4 + kc) * 64 + lane];

    const int pbase = (n0 >> 4) + wc * 4;   // first k-panel for this wave's half

    #pragma unroll 1
    for (int t = 0; t < NT_BLK; ++t) {
        const int nb = n0 + t * BN;

        f32x4 acc[2][4];
        #pragma unroll
        for (int i = 0; i < 2; ++i)
            #pragma unroll
            for (int j = 0; j < 4; ++j) {
                acc[i][j][0] = 0.f; acc[i][j][1] = 0.f;
                acc[i][j][2] = 0.f; acc[i][j][3] = 0.f;
            }

        #pragma unroll
        for (int kc = 0; kc < 4; ++kc) {
            f16x8 bh[4];
            #pragma unroll
            for (int j = 0; j < 4; ++j)
                bh[j] = *(const f16x8*)&kp[(size_t)((pbase + t * 8 + j) * 4 + kc) * 64 + lane];
            #pragma unroll
            for (int i = 0; i < 2; ++i)
                #pragma unroll
                for (int j = 0; j < 4; ++j)
                    acc[i][j] = __builtin_amdgcn_mfma_f32_16x16x32_f16(aq[i][kc], bh[j], acc[i][j], 0, 0, 0);
        }

        // fold row-max, DPP-share, gated append of near-max records
        #pragma unroll
        for (int e = 0; e < 8; ++e) {
            const int i = e >> 2, rr = e & 3;
            const float me = fmaxf(fmaxf(fmaxf(acc[i][0][rr], acc[i][1][rr]),
                                         acc[i][2][rr]), acc[i][3][rr]);
            L[e] = rowmax16(fmaxf(L[e], me));
            const float th = L[e] - mgv[e];
            if (me >= th) {
                const int row = q0 + wr * 32 + i * 16 + lg * 4 + rr;
                #pragma unroll
                for (int j = 0; j < 4; ++j) {
                    const float v = acc[i][j][rr];
                    if (v >= th) {
                        const int n = nb + wc * 64 + j * 16 + l15;
                        const int pos = atomicAdd(&lcnt, 1);
                        if (pos < LCAP)
                            lbuf[pos] = ((unsigned long long)ord_f32(v) << 32)
                                      | (unsigned int)((row << 15) | n);
                    }
                }
            }
        }
    }

    // publish per-row f16-score maxima (L[e] uniform across 16-lane row group)
    if (l15 == 0) {
        #pragma unroll
        for (int e = 0; e < 8; ++e) {
            const int row = q0 + wr * 32 + (e >> 2) * 16 + lg * 4 + (e & 3);
            atomicMax(&glb[row], ord_f32(L[e]));
        }
    }

    // flush records: ONE global atomic per block
    __syncthreads();
    const int total = lcnt;
    const int nout  = total < LCAP ? total : LCAP;
    if (tid == 0) {
        const int base = atomicAdd(&cnt[0], nout);
        sbase = base;
        if (total > LCAP || base + nout > CAND_CAP) atomicOr(&cnt[1], 1);
    }
    __syncthreads();
    for (int c = tid; c < nout; c += 512) {
        const int g = sbase + c;
        if (g < CAND_CAP) recs[g] = lbuf[c];
    }
}

// ---------------- fused filter+rescore [R12/R14-verified verbatim] ----
__global__ void filter_rescore_kernel(const unsigned long long* __restrict__ recs,
                                      const unsigned int* __restrict__ glb,
                                      const float* __restrict__ mg_g,
                                      int* __restrict__ cnt,
                                      const float* __restrict__ Q, const float* __restrict__ Kb,
                                      const float* __restrict__ ik,
                                      unsigned long long* __restrict__ best2)
{
    __shared__ unsigned int sb[2048];
    __shared__ int sc;
    const int tid = threadIdx.x;
    if (tid == 0) sc = 0;
    __syncthreads();

    const int cn = cnt[0];
    const int count = cn < CAND_CAP ? cn : CAND_CAP;
    const int nthr = gridDim.x * blockDim.x;
    for (int c = blockIdx.x * blockDim.x + tid; c < count; c += nthr) {
        const unsigned long long rec = recs[c];
        const unsigned int lo = (unsigned int)rec;
        const int q = (int)(lo >> 15);
        const float s = ord_inv((unsigned int)(rec >> 32));
        const unsigned int g = glb[q];
        const float M = g ? ord_inv(g) : 3e38f;   // unwritten row -> no survivors; safety rescues
        if (s >= M - mg_g[q]) {
            const int pos = atomicAdd(&sc, 1);
            if (pos < 2048) sb[pos] = lo;
        }
    }
    __syncthreads();
    const int total = sc;
    const int nout  = total < 2048 ? total : 2048;
    if (total > 2048 && tid == 0) atomicOr(&cnt[1], 2);   // overflow -> bad path

    const int lane = tid & 63;
    const int l15  = lane & 15;
    const int grp  = (tid >> 6) * 4 + (lane >> 4);
    const int ngrp = (blockDim.x >> 6) * 4;
    for (int c = grp; c < nout; c += ngrp) {
        const unsigned int lo = sb[c];
        const int q = (int)(lo >> 15), n = (int)(lo & 32767u);
        const float4* qpr = (const float4*)(Q  + (size_t)q * KD);
        const float4* kpr = (const float4*)(Kb + (size_t)n * KD);
        const float4 qa = qpr[l15 * 2], qb = qpr[l15 * 2 + 1];
        const float4 ka = kpr[l15 * 2], kb = kpr[l15 * 2 + 1];
        float dot = qa.x * ka.x + qa.y * ka.y + qa.z * ka.z + qa.w * ka.w
                  + qb.x * kb.x + qb.y * kb.y + qb.z * kb.z + qb.w * kb.w;
        #pragma unroll
        for (int m = 8; m; m >>= 1) dot += __shfl_xor(dot, m, 16);
        if (l15 == 0) {
            const float v = dot * ik[n];
            const unsigned long long pk =
                ((unsigned long long)ord_f32(v) << 32) | (unsigned int)(~n);
            atomicMax(&best2[q], pk);
        }
    }
}

// ---------------- fused safety+decode [R12/R14-verified verbatim] ----
__global__ void safety_decode_kernel(const float* __restrict__ Q, const float* __restrict__ Kb,
                                     const float* __restrict__ ik, const int* __restrict__ cnt,
                                     const unsigned long long* __restrict__ best2,
                                     int* __restrict__ out) {
    const int lane = threadIdx.x & 63;
    const int wid  = (blockIdx.x * blockDim.x + threadIdx.x) >> 6;
    const int nw   = (gridDim.x * blockDim.x) >> 6;
    const bool bad = (cnt[1] != 0) || (cnt[0] > CAND_CAP);
    for (int q = wid; q < B_Q; q += nw) {
        const unsigned long long b = best2[q];
        if (!bad && b != 0ull) {
            if (lane == 0) out[q] = (int)(~(unsigned int)(b & 0xFFFFFFFFull));
            continue;
        }
        // exhaustive exact scan (never taken for bench inputs)
        const float* qr = Q + (size_t)q * KD;
        unsigned long long pb = 0ull;
        for (int n = lane; n < N_SLOTS; n += 64) {
            const float* kr = Kb + (size_t)n * KD;
            float dot = 0.f;
            for (int d = 0; d < KD; ++d) dot = fmaf(qr[d], kr[d], dot);
            const float v = dot * ik[n];
            const unsigned long long p =
                ((unsigned long long)ord_f32(v) << 32) | (unsigned int)(~n);
            if (p > pb) pb = p;
        }
        #pragma unroll
        for (int m = 32; m; m >>= 1) {
            const unsigned long long o = shfl_xor_u64(pb, m, 64);
            if (o > pb) pb = o;
        }
        if (lane == 0) out[q] = (int)(~(unsigned int)(pb & 0xFFFFFFFFull));
    }
}

// ---------------- ws-too-small fallback: slow but correct ----------------
__global__ void fallback_kernel(const float* __restrict__ Q, const float* __restrict__ Kb,
                                int* __restrict__ out) {
    __shared__ float q[KD];
    __shared__ unsigned long long red[256];
    const int b = blockIdx.x;
    for (int i = threadIdx.x; i < KD; i += 256) q[i] = Q[(size_t)b * KD + i];
    __syncthreads();
    unsigned long long pbest = 0ull;
    for (int n = threadIdx.x; n < N_SLOTS; n += 256) {
        const float* kr = Kb + (size_t)n * KD;
        float dot = 0.f, ss = 0.f;
        for (int d = 0; d < KD; ++d) { float kv = kr[d]; dot = fmaf(q[d], kv, dot); ss = fmaf(kv, kv, ss); }
        float v = dot / fmaxf(sqrtf(ss), 1e-12f);
        unsigned long long p = ((unsigned long long)ord_f32(v) << 32) | (unsigned int)(~n);
        if (p > pbest) pbest = p;
    }
    red[threadIdx.x] = pbest; __syncthreads();
    for (int s = 128; s; s >>= 1) {
        if (threadIdx.x < (unsigned)s && red[threadIdx.x + s] > red[threadIdx.x])
            red[threadIdx.x] = red[threadIdx.x + s];
        __syncthreads();
    }
    if (threadIdx.x == 0) out[b] = (int)(~(unsigned int)(red[0] & 0xFFFFFFFFull));
}

extern "C" void kernel_launch(void* const* d_in, const int* in_sizes, int n_in,
                              void* d_out, int out_size, void* d_ws, size_t ws_size,
                              hipStream_t stream) {
    const float* Q  = (const float*)d_in[0];   // 4096 x 128
    const float* Kb = (const float*)d_in[1];   // 32768 x 128
    int* out = (int*)d_out;

    const size_t QP_B = (size_t)B_Q * KD * 2;        // 1 MB packed Q (f16)
    const size_t KP_B = (size_t)N_SLOTS * KD * 2;    // 8 MB packed K (f16)
    const size_t MG_B = (size_t)B_Q * 4;             // 16 KB
    const size_t IK_B = (size_t)N_SLOTS * 4;         // 128 KB
    const size_t GL_B = (size_t)B_Q * 4;             // 16 KB
    const size_t B2_B = (size_t)B_Q * 8;             // 32 KB
    const size_t CNT_B = 256;
    const size_t REC_B = (size_t)CAND_CAP * 8;       // 8 MB
    const size_t NEED = QP_B + KP_B + MG_B + IK_B + GL_B + B2_B + CNT_B + REC_B;

    if (ws_size < NEED) {
        fallback_kernel<<<B_Q, 256, 0, stream>>>(Q, Kb, out);
        return;
    }

    char* p = (char*)d_ws;
    uint4*          qp  = (uint4*)p;                     p += QP_B;
    uint4*          kp  = (uint4*)p;                     p += KP_B;
    float*          mg  = (float*)p;                     p += MG_B;
    float*          ik  = (float*)p;                     p += IK_B;
    unsigned int*   glb = (unsigned int*)p;              p += GL_B;
    unsigned long long* best2 = (unsigned long long*)p;  p += B2_B;
    int*            cnt = (int*)p;                       p += CNT_B;
    unsigned long long* recs = (unsigned long long*)p;

    prep_pack<<<KPANELS + QPANELS, 256, 0, stream>>>(Q, Kb, qp, kp, mg, ik, glb, best2, cnt);
    pass1_kernel<<<512, 512, 0, stream>>>(qp, kp, mg, glb, cnt, recs);
    filter_rescore_kernel<<<256, 256, 0, stream>>>(recs, glb, mg, cnt, Q, Kb, ik, best2);
    safety_decode_kernel<<<64, 256, 0, stream>>>(Q, Kb, ik, cnt, best2, out);
}

// Round 17
// 85.447 us; speedup vs baseline: 2.1836x; 1.0129x over previous
//
#include <hip/hip_runtime.h>
#include <stdint.h>

#define B_Q     4096
#define N_SLOTS 32768
#define KD      128
#define BM      128
#define BN      128
#define NSPLIT  16
#define NCHUNK  (N_SLOTS / NSPLIT)   // 2048 cols per block
#define NT_BLK  (NCHUNK / BN)        // 16 tiles per block
#define CAND_CAP (1 << 20)           // 1M record cap (u64)
#define LCAP    6144                 // per-block LDS record cap (48 KB)
#define KPANELS (N_SLOTS / 16)       // 2048
#define QPANELS (B_Q / 16)           // 256

typedef _Float16 f16x8 __attribute__((ext_vector_type(8)));
typedef float    f32x4 __attribute__((ext_vector_type(4)));

// ordered-float: monotone f32 <-> u32
__device__ __forceinline__ unsigned int ord_f32(float f) {
    unsigned int u = __float_as_uint(f);
    return (u & 0x80000000u) ? ~u : (u | 0x80000000u);
}
__device__ __forceinline__ float ord_inv(unsigned int u) {
    unsigned int b = (u & 0x80000000u) ? (u & 0x7FFFFFFFu) : ~u;
    return __uint_as_float(b);
}

__device__ __forceinline__ unsigned long long shfl_xor_u64(unsigned long long v, int mask, int width) {
    unsigned int lo = (unsigned int)v, hi = (unsigned int)(v >> 32);
    lo = __shfl_xor(lo, mask, width);
    hi = __shfl_xor(hi, mask, width);
    return ((unsigned long long)hi << 32) | lo;
}

// max over the 16-lane DPP row via 4x ROW_ROR rotate-reduce (no LDS traffic)
__device__ __forceinline__ float rowmax16(float x) {
    x = fmaxf(x, __int_as_float(__builtin_amdgcn_mov_dpp(__float_as_int(x), 0x128, 0xf, 0xf, true)));
    x = fmaxf(x, __int_as_float(__builtin_amdgcn_mov_dpp(__float_as_int(x), 0x124, 0xf, 0xf, true)));
    x = fmaxf(x, __int_as_float(__builtin_amdgcn_mov_dpp(__float_as_int(x), 0x122, 0xf, 0xf, true)));
    x = fmaxf(x, __int_as_float(__builtin_amdgcn_mov_dpp(__float_as_int(x), 0x121, 0xf, 0xf, true)));
    return x;
}

// ---------------- prep: normalize K, f16-convert, pack into MFMA-fragment order ----
// [R10/R14/R16-verified verbatim]
__global__ void prep_pack(const float* __restrict__ Q, const float* __restrict__ Kb,
                          uint4* __restrict__ qp, uint4* __restrict__ kp,
                          float* __restrict__ mg, float* __restrict__ ik,
                          unsigned int* __restrict__ glb,
                          unsigned long long* __restrict__ best2, int* __restrict__ cnt) {
    const int gid = blockIdx.x * blockDim.x + threadIdx.x;
    if (gid < B_Q) { best2[gid] = 0ull; glb[gid] = 0u; }
    if (gid == 0) { cnt[0] = 0; cnt[1] = 0; cnt[2] = 0; cnt[3] = 0; }

    const int p = blockIdx.x;            // panel id: [0,KPANELS) K, then Q
    const int t = threadIdx.x;           // r = t>>4 rows, c = t&15 k-16ths
    const int r = t >> 4, c = t & 15;
    const bool isK = p < KPANELS;
    const int row = isK ? p * 16 + r : (p - KPANELS) * 16 + r;
    const float* src = isK ? Kb : Q;
    const float4* rp = reinterpret_cast<const float4*>(src + (size_t)row * KD);
    const float4 va = rp[c * 2], vb = rp[c * 2 + 1];   // els k = c*8 .. c*8+7
    float ss = va.x * va.x + va.y * va.y + va.z * va.z + va.w * va.w
             + vb.x * vb.x + vb.y * vb.y + vb.z * vb.z + vb.w * vb.w;
    #pragma unroll
    for (int m = 8; m; m >>= 1) ss += __shfl_xor(ss, m, 16);   // 16 threads per row
    const float nrm = fmaxf(sqrtf(ss), 1e-12f);
    const float scale = isK ? 1.0f / nrm : 1.0f;
    if (c == 0) {
        if (isK) ik[row] = scale;
        else     mg[row] = nrm * 2.2e-3f;   // rigorous: >= 2*eps_f16dot (2^-10*||q||)
    }
    unsigned short h[8];
    const float e[8] = {va.x, va.y, va.z, va.w, vb.x, vb.y, vb.z, vb.w};
    #pragma unroll
    for (int i = 0; i < 8; ++i) {
        _Float16 hv = (_Float16)(e[i] * scale);
        __builtin_memcpy(&h[i], &hv, 2);
    }
    uint4 out;
    out.x = (unsigned)h[0] | ((unsigned)h[1] << 16);
    out.y = (unsigned)h[2] | ((unsigned)h[3] << 16);
    out.z = (unsigned)h[4] | ((unsigned)h[5] << 16);
    out.w = (unsigned)h[6] | ((unsigned)h[7] << 16);
    uint4* dst = isK ? kp : qp;
    const int pl = isK ? p : p - KPANELS;
    dst[(size_t)(pl * 4 + (c >> 2)) * 64 + (c & 3) * 16 + r] = out;
}

// ---------------- pass 1: f16 MFMA GEMM (packed global frags) + margin records ----
// [R10/R14/R16 structure; two bit-exact VALU trims:]
//  (a) kc=0 peeled: acc initialized by mfma(A,B,0) -> no per-tile accvgpr zeroing
//  (b) epilogue any-skip: rowmax16+scan skipped when provably no-op
//      (no lane has me >= L - mg  =>  fmax(L,me)=L, rowmax16(L)=L, gate false)
// 512 blocks x 512 threads (8 waves). Wave w: rows q0+(w>>1)*32, cols n0+(w&1)*64.
// XCD decode: xcd=bid&7 owns n-chunks {2*xcd, 2*xcd+1}.
__global__ __launch_bounds__(512, 4) void pass1_kernel(
    const uint4* __restrict__ qp, const uint4* __restrict__ kp,
    const float* __restrict__ mg_g, unsigned int* __restrict__ glb,
    int* __restrict__ cnt, unsigned long long* __restrict__ recs)
{
    __shared__ unsigned long long lbuf[LCAP];
    __shared__ int lcnt;
    __shared__ int sbase;

    const int bid  = blockIdx.x;
    const int q0   = (bid >> 4) * BM;
    const int n0   = ((bid & 7) * 2 + ((bid >> 3) & 1)) * NCHUNK;
    const int tid  = threadIdx.x;
    const int lane = tid & 63;
    const int w    = tid >> 6;      // 0..7
    const int wr   = w >> 1;        // 0..3: row group (32 rows)
    const int wc   = w & 1;         // 0..1: col group (64 cols)
    const int l15  = lane & 15;
    const int lg   = lane >> 4;

    if (tid == 0) lcnt = 0;
    __syncthreads();

    // per-lane owned rows: row(e) = q0 + wr*32 + (e>>2)*16 + lg*4 + (e&3), e<8
    float L[8], mgv[8];
    #pragma unroll
    for (int e = 0; e < 8; ++e) {
        const int row = q0 + wr * 32 + (e >> 2) * 16 + lg * 4 + (e & 3);
        mgv[e] = mg_g[row];
        const unsigned int g = glb[row];
        L[e] = g ? ord_inv(g) : -3e38f;
    }

    // A fragments (Q) cached in registers: panels (q0>>4) + wr*2 + i
    f16x8 aq[2][4];
    #pragma unroll
    for (int i = 0; i < 2; ++i)
        #pragma unroll
        for (int kc = 0; kc < 4; ++kc)
            aq[i][kc] = *(const f16x8*)&qp[(size_t)(((q0 >> 4) + wr * 2 + i) * 4 + kc) * 64 + lane];

    const int pbase = (n0 >> 4) + wc * 4;   // first k-panel for this wave's half

    const f32x4 zc = {0.f, 0.f, 0.f, 0.f};  // zero C operand for kc=0 init

    #pragma unroll 1
    for (int t = 0; t < NT_BLK; ++t) {
        const int nb = n0 + t * BN;

        f32x4 acc[2][4];

        // kc = 0: initialize acc directly via MFMA with zero C (no accvgpr zeroing)
        {
            f16x8 bh[4];
            #pragma unroll
            for (int j = 0; j < 4; ++j)
                bh[j] = *(const f16x8*)&kp[(size_t)((pbase + t * 8 + j) * 4 + 0) * 64 + lane];
            #pragma unroll
            for (int i = 0; i < 2; ++i)
                #pragma unroll
                for (int j = 0; j < 4; ++j)
                    acc[i][j] = __builtin_amdgcn_mfma_f32_16x16x32_f16(aq[i][0], bh[j], zc, 0, 0, 0);
        }

        #pragma unroll
        for (int kc = 1; kc < 4; ++kc) {
            f16x8 bh[4];
            #pragma unroll
            for (int j = 0; j < 4; ++j)
                bh[j] = *(const f16x8*)&kp[(size_t)((pbase + t * 8 + j) * 4 + kc) * 64 + lane];
            #pragma unroll
            for (int i = 0; i < 2; ++i)
                #pragma unroll
                for (int j = 0; j < 4; ++j)
                    acc[i][j] = __builtin_amdgcn_mfma_f32_16x16x32_f16(aq[i][kc], bh[j], acc[i][j], 0, 0, 0);
        }

        // epilogue: fold per-lane tile max; skip share+scan when provably no-op
        #pragma unroll
        for (int e = 0; e < 8; ++e) {
            const int i = e >> 2, rr = e & 3;
            const float me = fmaxf(fmaxf(acc[i][0][rr], acc[i][1][rr]),
                                   fmaxf(acc[i][2][rr], acc[i][3][rr]));
            if (__any(me >= L[e] - mgv[e])) {       // wave-uniform branch
                L[e] = rowmax16(fmaxf(L[e], me));
                const float th = L[e] - mgv[e];
                if (me >= th) {
                    const int row = q0 + wr * 32 + i * 16 + lg * 4 + rr;
                    #pragma unroll
                    for (int j = 0; j < 4; ++j) {
                        const float v = acc[i][j][rr];
                        if (v >= th) {
                            const int n = nb + wc * 64 + j * 16 + l15;
                            const int pos = atomicAdd(&lcnt, 1);
                            if (pos < LCAP)
                                lbuf[pos] = ((unsigned long long)ord_f32(v) << 32)
                                          | (unsigned int)((row << 15) | n);
                        }
                    }
                }
            }
        }
    }

    // publish per-row f16-score maxima (L[e] uniform across 16-lane row group)
    if (l15 == 0) {
        #pragma unroll
        for (int e = 0; e < 8; ++e) {
            const int row = q0 + wr * 32 + (e >> 2) * 16 + lg * 4 + (e & 3);
            atomicMax(&glb[row], ord_f32(L[e]));
        }
    }

    // flush records: ONE global atomic per block
    __syncthreads();
    const int total = lcnt;
    const int nout  = total < LCAP ? total : LCAP;
    if (tid == 0) {
        const int base = atomicAdd(&cnt[0], nout);
        sbase = base;
        if (total > LCAP || base + nout > CAND_CAP) atomicOr(&cnt[1], 1);
    }
    __syncthreads();
    for (int c = tid; c < nout; c += 512) {
        const int g = sbase + c;
        if (g < CAND_CAP) recs[g] = lbuf[c];
    }
}

// ---------------- fused filter+rescore [R12/R14/R16-verified verbatim] ----
__global__ void filter_rescore_kernel(const unsigned long long* __restrict__ recs,
                                      const unsigned int* __restrict__ glb,
                                      const float* __restrict__ mg_g,
                                      int* __restrict__ cnt,
                                      const float* __restrict__ Q, const float* __restrict__ Kb,
                                      const float* __restrict__ ik,
                                      unsigned long long* __restrict__ best2)
{
    __shared__ unsigned int sb[2048];
    __shared__ int sc;
    const int tid = threadIdx.x;
    if (tid == 0) sc = 0;
    __syncthreads();

    const int cn = cnt[0];
    const int count = cn < CAND_CAP ? cn : CAND_CAP;
    const int nthr = gridDim.x * blockDim.x;
    for (int c = blockIdx.x * blockDim.x + tid; c < count; c += nthr) {
        const unsigned long long rec = recs[c];
        const unsigned int lo = (unsigned int)rec;
        const int q = (int)(lo >> 15);
        const float s = ord_inv((unsigned int)(rec >> 32));
        const unsigned int g = glb[q];
        const float M = g ? ord_inv(g) : 3e38f;   // unwritten row -> no survivors; safety rescues
        if (s >= M - mg_g[q]) {
            const int pos = atomicAdd(&sc, 1);
            if (pos < 2048) sb[pos] = lo;
        }
    }
    __syncthreads();
    const int total = sc;
    const int nout  = total < 2048 ? total : 2048;
    if (total > 2048 && tid == 0) atomicOr(&cnt[1], 2);   // overflow -> bad path

    const int lane = tid & 63;
    const int l15  = lane & 15;
    const int grp  = (tid >> 6) * 4 + (lane >> 4);
    const int ngrp = (blockDim.x >> 6) * 4;
    for (int c = grp; c < nout; c += ngrp) {
        const unsigned int lo = sb[c];
        const int q = (int)(lo >> 15), n = (int)(lo & 32767u);
        const float4* qpr = (const float4*)(Q  + (size_t)q * KD);
        const float4* kpr = (const float4*)(Kb + (size_t)n * KD);
        const float4 qa = qpr[l15 * 2], qb = qpr[l15 * 2 + 1];
        const float4 ka = kpr[l15 * 2], kb = kpr[l15 * 2 + 1];
        float dot = qa.x * ka.x + qa.y * ka.y + qa.z * ka.z + qa.w * ka.w
                  + qb.x * kb.x + qb.y * kb.y + qb.z * kb.z + qb.w * kb.w;
        #pragma unroll
        for (int m = 8; m; m >>= 1) dot += __shfl_xor(dot, m, 16);
        if (l15 == 0) {
            const float v = dot * ik[n];
            const unsigned long long pk =
                ((unsigned long long)ord_f32(v) << 32) | (unsigned int)(~n);
            atomicMax(&best2[q], pk);
        }
    }
}

// ---------------- fused safety+decode [R12/R14/R16-verified verbatim] ----
__global__ void safety_decode_kernel(const float* __restrict__ Q, const float* __restrict__ Kb,
                                     const float* __restrict__ ik, const int* __restrict__ cnt,
                                     const unsigned long long* __restrict__ best2,
                                     int* __restrict__ out) {
    const int lane = threadIdx.x & 63;
    const int wid  = (blockIdx.x * blockDim.x + threadIdx.x) >> 6;
    const int nw   = (gridDim.x * blockDim.x) >> 6;
    const bool bad = (cnt[1] != 0) || (cnt[0] > CAND_CAP);
    for (int q = wid; q < B_Q; q += nw) {
        const unsigned long long b = best2[q];
        if (!bad && b != 0ull) {
            if (lane == 0) out[q] = (int)(~(unsigned int)(b & 0xFFFFFFFFull));
            continue;
        }
        // exhaustive exact scan (never taken for bench inputs)
        const float* qr = Q + (size_t)q * KD;
        unsigned long long pb = 0ull;
        for (int n = lane; n < N_SLOTS; n += 64) {
            const float* kr = Kb + (size_t)n * KD;
            float dot = 0.f;
            for (int d = 0; d < KD; ++d) dot = fmaf(qr[d], kr[d], dot);
            const float v = dot * ik[n];
            const unsigned long long p =
                ((unsigned long long)ord_f32(v) << 32) | (unsigned int)(~n);
            if (p > pb) pb = p;
        }
        #pragma unroll
        for (int m = 32; m; m >>= 1) {
            const unsigned long long o = shfl_xor_u64(pb, m, 64);
            if (o > pb) pb = o;
        }
        if (lane == 0) out[q] = (int)(~(unsigned int)(pb & 0xFFFFFFFFull));
    }
}

// ---------------- ws-too-small fallback: slow but correct ----------------
__global__ void fallback_kernel(const float* __restrict__ Q, const float* __restrict__ Kb,
                                int* __restrict__ out) {
    __shared__ float q[KD];
    __shared__ unsigned long long red[256];
    const int b = blockIdx.x;
    for (int i = threadIdx.x; i < KD; i += 256) q[i] = Q[(size_t)b * KD + i];
    __syncthreads();
    unsigned long long pbest = 0ull;
    for (int n = threadIdx.x; n < N_SLOTS; n += 256) {
        const float* kr = Kb + (size_t)n * KD;
        float dot = 0.f, ss = 0.f;
        for (int d = 0; d < KD; ++d) { float kv = kr[d]; dot = fmaf(q[d], kv, dot); ss = fmaf(kv, kv, ss); }
        float v = dot / fmaxf(sqrtf(ss), 1e-12f);
        unsigned long long p = ((unsigned long long)ord_f32(v) << 32) | (unsigned int)(~n);
        if (p > pbest) pbest = p;
    }
    red[threadIdx.x] = pbest; __syncthreads();
    for (int s = 128; s; s >>= 1) {
        if (threadIdx.x < (unsigned)s && red[threadIdx.x + s] > red[threadIdx.x])
            red[threadIdx.x] = red[threadIdx.x + s];
        __syncthreads();
    }
    if (threadIdx.x == 0) out[b] = (int)(~(unsigned int)(red[0] & 0xFFFFFFFFull));
}

extern "C" void kernel_launch(void* const* d_in, const int* in_sizes, int n_in,
                              void* d_out, int out_size, void* d_ws, size_t ws_size,
                              hipStream_t stream) {
    const float* Q  = (const float*)d_in[0];   // 4096 x 128
    const float* Kb = (const float*)d_in[1];   // 32768 x 128
    int* out = (int*)d_out;

    const size_t QP_B = (size_t)B_Q * KD * 2;        // 1 MB packed Q (f16)
    const size_t KP_B = (size_t)N_SLOTS * KD * 2;    // 8 MB packed K (f16)
    const size_t MG_B = (size_t)B_Q * 4;             // 16 KB
    const size_t IK_B = (size_t)N_SLOTS * 4;         // 128 KB
    const size_t GL_B = (size_t)B_Q * 4;             // 16 KB
    const size_t B2_B = (size_t)B_Q * 8;             // 32 KB
    const size_t CNT_B = 256;
    const size_t REC_B = (size_t)CAND_CAP * 8;       // 8 MB
    const size_t NEED = QP_B + KP_B + MG_B + IK_B + GL_B + B2_B + CNT_B + REC_B;

    if (ws_size < NEED) {
        fallback_kernel<<<B_Q, 256, 0, stream>>>(Q, Kb, out);
        return;
    }

    char* p = (char*)d_ws;
    uint4*          qp  = (uint4*)p;                     p += QP_B;
    uint4*          kp  = (uint4*)p;                     p += KP_B;
    float*          mg  = (float*)p;                     p += MG_B;
    float*          ik  = (float*)p;                     p += IK_B;
    unsigned int*   glb = (unsigned int*)p;              p += GL_B;
    unsigned long long* best2 = (unsigned long long*)p;  p += B2_B;
    int*            cnt = (int*)p;                       p += CNT_B;
    unsigned long long* recs = (unsigned long long*)p;

    prep_pack<<<KPANELS + QPANELS, 256, 0, stream>>>(Q, Kb, qp, kp, mg, ik, glb, best2, cnt);
    pass1_kernel<<<512, 512, 0, stream>>>(qp, kp, mg, glb, cnt, recs);
    filter_rescore_kernel<<<256, 256, 0, stream>>>(recs, glb, mg, cnt, Q, Kb, ik, best2);
    safety_decode_kernel<<<64, 256, 0, stream>>>(Q, Kb, ik, cnt, best2, out);
}